// Round 4
// baseline (565.544 us; speedup 1.0000x reference)
//
#include <hip/hip_runtime.h>

#define AS1 __attribute__((address_space(1)))
#define AS3 __attribute__((address_space(3)))

typedef __bf16 bf16_t;
typedef __bf16 bf16x8 __attribute__((ext_vector_type(8)));
typedef __bf16 bf16x4 __attribute__((ext_vector_type(4)));
typedef float  floatx4 __attribute__((ext_vector_type(4)));

#define MFMA_BF16(a, b, c) __builtin_amdgcn_mfma_f32_16x16x32_bf16(a, b, c, 0, 0, 0)

static constexpr int T_  = 2048;
static constexpr int D_  = 3584;
static constexpr int NH_ = 28;   // query heads
static constexpr int KV_ = 4;    // kv heads
static constexpr int H_  = 128;  // head dim
static constexpr int NW_ = 36;   // 28 q + 4 k + 4 v projection heads
static constexpr int FPH_ = 40;  // split-s work items per head: sum_qb ceil((qb+1)/4)

// ---------------------------------------------------------------------------
// Elementwise fp32 -> bf16 convert (8 elems/thread)
// ---------------------------------------------------------------------------
__global__ void convert_f32_bf16(const float* __restrict__ src, bf16_t* __restrict__ dst) {
    const long i = (long)(blockIdx.x * blockDim.x + threadIdx.x) * 8;
    float4 a = ((const float4*)(src + i))[0];
    float4 b = ((const float4*)(src + i))[1];
    bf16x8 o = {(bf16_t)a.x, (bf16_t)a.y, (bf16_t)a.z, (bf16_t)a.w,
                (bf16_t)b.x, (bf16_t)b.y, (bf16_t)b.z, (bf16_t)b.w};
    *(bf16x8*)(dst + i) = o;
}

// ---------------------------------------------------------------------------
// 64x64-tile fp32 -> bf16 transpose, vectorized: dst[c][r] = (bf16)src[r][c]
// Loads float4, LDS b64 writes, b128 stores.
// ---------------------------------------------------------------------------
__global__ __launch_bounds__(256) void transpose64_f32_bf16(const float* __restrict__ src,
                                                            bf16_t* __restrict__ dst,
                                                            int R, int C, long sStride, long dStride) {
    __shared__ bf16_t t[64][68];
    src += (long)blockIdx.z * sStride;
    dst += (long)blockIdx.z * dStride;
    const int tid = threadIdx.x;
    const int r0 = blockIdx.y * 64, c0 = blockIdx.x * 64;
#pragma unroll
    for (int p = 0; p < 4; p++) {
        const int row = (tid >> 4) + p * 16, col4 = tid & 15;
        float4 v = *(const float4*)(src + (long)(r0 + row) * C + c0 + col4 * 4);
        bf16x4 b = {(bf16_t)v.x, (bf16_t)v.y, (bf16_t)v.z, (bf16_t)v.w};
        *(bf16x4*)&t[row][col4 * 4] = b;
    }
    __syncthreads();
#pragma unroll
    for (int p = 0; p < 2; p++) {
        const int cc = (tid >> 3) + p * 32, k = tid & 7;
        bf16x8 o;
#pragma unroll
        for (int j = 0; j < 8; j++) o[j] = t[8 * k + j][cc];
        *(bf16x8*)(dst + (long)(c0 + cc) * R + r0 + 8 * k) = o;
    }
}

// ---------------------------------------------------------------------------
// Small 32x32 bf16 transpose (used for V^T only, 2 MB)
// ---------------------------------------------------------------------------
__global__ void transpose32_bf16(const bf16_t* __restrict__ src, bf16_t* __restrict__ dst,
                                 int R, int C, long sStride, long dStride) {
    __shared__ bf16_t tile[32][33];
    src += (long)blockIdx.z * sStride;
    dst += (long)blockIdx.z * dStride;
    const int tx = threadIdx.x & 31, ty = threadIdx.x >> 5;
    const int r0 = blockIdx.y * 32, c0 = blockIdx.x * 32;
#pragma unroll
    for (int i = 0; i < 4; i++) {
        int rr = ty + i * 8;
        tile[rr][tx] = src[(long)(r0 + rr) * C + c0 + tx];
    }
    __syncthreads();
#pragma unroll
    for (int i = 0; i < 4; i++) {
        int cc = ty + i * 8;
        dst[(long)(c0 + cc) * R + r0 + tx] = tile[tx][cc];
    }
}

// ---------------------------------------------------------------------------
// m97-style 128x128 GEMM core: C = A[128 x K] * Bt[128 x K]^T, fp32 acc.
// ---------------------------------------------------------------------------
__device__ __forceinline__ void gemm_core_128x128(const bf16_t* __restrict__ Arows, int lda,
                                                  const bf16_t* __restrict__ Brows, int ldb,
                                                  int K, floatx4 acc[4][4]) {
    __shared__ bf16_t As[128 * 32];
    __shared__ bf16_t Bs[128 * 32];
    const int tid = threadIdx.x;
    const int w = tid >> 6, l = tid & 63;
    const int lr = l >> 2, lc = l & 3;
    const int m16 = l & 15, quad = l >> 4;
    const int wr = w >> 1, wc = w & 1;
#pragma unroll
    for (int i = 0; i < 4; i++)
#pragma unroll
        for (int j = 0; j < 4; j++) acc[i][j] = (floatx4){0.f, 0.f, 0.f, 0.f};

    for (int kt = 0; kt < K; kt += 32) {
        __syncthreads();
#pragma unroll
        for (int is = 0; is < 2; is++) {
            const int row = 32 * w + 16 * is + lr;
            __builtin_amdgcn_global_load_lds((const AS1 void*)(Arows + (long)row * lda + kt + lc * 8),
                                             (AS3 void*)(As + row * 32 + lc * 8), 16, 0, 0);
            __builtin_amdgcn_global_load_lds((const AS1 void*)(Brows + (long)row * ldb + kt + lc * 8),
                                             (AS3 void*)(Bs + row * 32 + lc * 8), 16, 0, 0);
        }
        __syncthreads();
        bf16x8 af[4], bfr[4];
#pragma unroll
        for (int i = 0; i < 4; i++)
            af[i] = *(const bf16x8*)(As + (64 * wr + 16 * i + m16) * 32 + quad * 8);
#pragma unroll
        for (int j = 0; j < 4; j++)
            bfr[j] = *(const bf16x8*)(Bs + (64 * wc + 16 * j + m16) * 32 + quad * 8);
#pragma unroll
        for (int i = 0; i < 4; i++)
#pragma unroll
            for (int j = 0; j < 4; j++) acc[i][j] = MFMA_BF16(af[i], bfr[j], acc[i][j]);
    }
}

// QKV projection: out[hd][t][h] = x[t][:] . w[hd][:][h] + bias[hd][h]
__global__ __launch_bounds__(256) void gemm_qkv_kernel(const bf16_t* __restrict__ X,
                                                       const bf16_t* __restrict__ Wt,
                                                       const float* __restrict__ bq,
                                                       const float* __restrict__ bk,
                                                       const float* __restrict__ bv,
                                                       bf16_t* __restrict__ out) {
    const int mt = blockIdx.x, hd = blockIdx.y;
    const float* bias = hd < NH_ ? bq + hd * H_
                                 : (hd < NH_ + KV_ ? bk + (hd - NH_) * H_ : bv + (hd - NH_ - KV_) * H_);
    floatx4 acc[4][4];
    gemm_core_128x128(X + (long)mt * 128 * D_, D_, Wt + (long)hd * H_ * D_, D_, D_, acc);
    const int l = threadIdx.x & 63, w = threadIdx.x >> 6;
    const int m16 = l & 15, quad = l >> 4, wr = w >> 1, wc = w & 1;
    bf16_t* C = out + (long)hd * T_ * H_ + (long)mt * 128 * H_;
#pragma unroll
    for (int j = 0; j < 4; j++) {
        const int col = 64 * wc + 16 * j + m16;
        const float bb = bias[col];
#pragma unroll
        for (int i = 0; i < 4; i++) {
            const int row = 64 * wr + 16 * i + quad * 4;
#pragma unroll
            for (int r = 0; r < 4; r++) C[(row + r) * H_ + col] = (bf16_t)(acc[i][j][r] + bb);
        }
    }
}

// Output projection: out[t][d] = ctx[t][:] . woT[d][:]  (fp32 output)
__global__ __launch_bounds__(256) void gemm_out_kernel(const bf16_t* __restrict__ A,
                                                       const bf16_t* __restrict__ Bt,
                                                       float* __restrict__ Cg) {
    const int mt = blockIdx.x, nt = blockIdx.y;
    floatx4 acc[4][4];
    gemm_core_128x128(A + (long)mt * 128 * D_, D_, Bt + (long)nt * 128 * D_, D_, D_, acc);
    const int l = threadIdx.x & 63, w = threadIdx.x >> 6;
    const int m16 = l & 15, quad = l >> 4, wr = w >> 1, wc = w & 1;
    float* C = Cg + (long)mt * 128 * D_ + nt * 128;
#pragma unroll
    for (int j = 0; j < 4; j++) {
        const int col = 64 * wc + 16 * j + m16;
#pragma unroll
        for (int i = 0; i < 4; i++) {
            const int row = 64 * wr + 16 * i + quad * 4;
#pragma unroll
            for (int r = 0; r < 4; r++) C[(long)(row + r) * D_ + col] = acc[i][j][r];
        }
    }
}

// ---------------------------------------------------------------------------
// In-place RoPE on q (heads 0..27, scaled by H^-0.5) and k (heads 28..31)
// ---------------------------------------------------------------------------
__global__ void rope_kernel(bf16_t* __restrict__ qkv, const int* __restrict__ pos) {
    const int idx = blockIdx.x * blockDim.x + threadIdx.x;
    const int h = idx & 63;
    const int t = (idx >> 6) & (T_ - 1);
    const int hd = idx >> 17;
    if (hd >= NH_ + KV_) return;
    bf16_t* p = qkv + ((long)hd * T_ + t) * H_;
    const float x1 = (float)p[h], x2 = (float)p[h + 64];
    const float inv = expf(-(float)h * (13.815510557964274f / 64.f));
    const float ang = (float)pos[t] * inv;
    float s, c;
    sincosf(ang, &s, &c);
    float o1 = x1 * c - x2 * s;
    float o2 = x2 * c + x1 * s;
    if (hd < NH_) { o1 *= 0.08838834764831845f; o2 *= 0.08838834764831845f; }
    p[h] = (bf16_t)o1;
    p[h + 64] = (bf16_t)o2;
}

// ---------------------------------------------------------------------------
// Split-s flash attention. Work item = (head, q-tile of 128, s-chunk of 512).
// Writes per-chunk normalized O (bf16) + (m,l) partials; combine_kernel merges.
// blockIdx.x = f in [0,40): decoded to (qb, chunk c) with c fastest.
// ---------------------------------------------------------------------------
__global__ __launch_bounds__(256, 3) void attn_kernel(const bf16_t* __restrict__ qkv,
                                                      const bf16_t* __restrict__ vT,
                                                      bf16_t* __restrict__ Opart,
                                                      float* __restrict__ ml) {
    __shared__ bf16_t smem[64 * 136 + 128 * 72 + 128 * 72];
    bf16_t* Ks = smem;
    bf16_t* Vs = smem + 64 * 136;
    bf16_t* Ps = Vs + 128 * 72;

    const int n = blockIdx.y;
    int qb = 0, rem = blockIdx.x;
    while (true) { int ch = (qb + 4) >> 2; if (rem < ch) break; rem -= ch; qb++; }
    const long pidx = (long)n * FPH_ + blockIdx.x;

    const int kvh = n / 7;
    const bf16_t* Q = qkv + (long)n * T_ * H_;
    const bf16_t* Kg = qkv + (long)(NH_ + kvh) * T_ * H_;
    const bf16_t* Vg = vT + (long)kvh * H_ * T_;  // [h][t]

    const int tid = threadIdx.x, w = tid >> 6, l = tid & 63;
    const int m16 = l & 15, quad = l >> 4;
    const int q0 = qb * 128 + w * 32;

    bf16x8 qf[2][4];
#pragma unroll
    for (int qt = 0; qt < 2; qt++)
#pragma unroll
        for (int kk = 0; kk < 4; kk++)
            qf[qt][kk] = *(const bf16x8*)(Q + (long)(q0 + qt * 16 + m16) * H_ + kk * 32 + quad * 8);

    floatx4 ot[2][8];
#pragma unroll
    for (int qt = 0; qt < 2; qt++)
#pragma unroll
        for (int ht = 0; ht < 8; ht++) ot[qt][ht] = (floatx4){0.f, 0.f, 0.f, 0.f};
    float mi[2] = {-1e30f, -1e30f}, li[2] = {0.f, 0.f};

    const int sb0 = rem * 8;
    const int sbE = min(sb0 + 8, 2 * qb + 2);
    const int ks_row = tid >> 2, ks_ck = (tid & 3) * 32;
    const int vs_row = tid >> 1, vs_hf = (tid & 1) * 32;

    // prefetch first tile into registers
    bf16x8 ka[4], va[4];
    {
        const bf16x8* g = (const bf16x8*)(Kg + ((long)sb0 * 64 + ks_row) * H_ + ks_ck);
#pragma unroll
        for (int i = 0; i < 4; i++) ka[i] = g[i];
        const bf16x8* gv = (const bf16x8*)(Vg + (long)vs_row * T_ + sb0 * 64 + vs_hf);
#pragma unroll
        for (int i = 0; i < 4; i++) va[i] = gv[i];
    }

    for (int sb = sb0; sb < sbE; sb++) {
        __syncthreads();
        {
            bf16x8* d = (bf16x8*)(Ks + ks_row * 136 + ks_ck);
#pragma unroll
            for (int i = 0; i < 4; i++) d[i] = ka[i];
            bf16x8* dv = (bf16x8*)(Vs + vs_row * 72 + vs_hf);
#pragma unroll
            for (int i = 0; i < 4; i++) dv[i] = va[i];
        }
        __syncthreads();
        if (sb + 1 < sbE) {  // prefetch next tile while computing
            const bf16x8* g = (const bf16x8*)(Kg + ((long)(sb + 1) * 64 + ks_row) * H_ + ks_ck);
#pragma unroll
            for (int i = 0; i < 4; i++) ka[i] = g[i];
            const bf16x8* gv = (const bf16x8*)(Vg + (long)vs_row * T_ + (sb + 1) * 64 + vs_hf);
#pragma unroll
            for (int i = 0; i < 4; i++) va[i] = gv[i];
        }

        // S^T[s][q] = sum_h K[s][h] Q[q][h]
        floatx4 stv[2][4];
#pragma unroll
        for (int ts = 0; ts < 4; ts++) {
            bf16x8 kf[4];
#pragma unroll
            for (int kk = 0; kk < 4; kk++)
                kf[kk] = *(const bf16x8*)(Ks + (16 * ts + m16) * 136 + kk * 32 + quad * 8);
#pragma unroll
            for (int qt = 0; qt < 2; qt++) {
                floatx4 c = (floatx4){0.f, 0.f, 0.f, 0.f};
#pragma unroll
                for (int kk = 0; kk < 4; kk++) c = MFMA_BF16(kf[kk], qf[qt][kk], c);
                stv[qt][ts] = c;
            }
        }

        const bool need_mask = (sb * 64 + 63) > q0;
#pragma unroll
        for (int qt = 0; qt < 2; qt++) {
            const int qg = q0 + qt * 16 + m16;
            if (need_mask) {
#pragma unroll
                for (int ts = 0; ts < 4; ts++)
#pragma unroll
                    for (int r = 0; r < 4; r++) {
                        const int sg = sb * 64 + ts * 16 + quad * 4 + r;
                        if (sg > qg) stv[qt][ts][r] = -1e30f;
                    }
            }
            float mx = -1e30f;
#pragma unroll
            for (int ts = 0; ts < 4; ts++)
#pragma unroll
                for (int r = 0; r < 4; r++) mx = fmaxf(mx, stv[qt][ts][r]);
            mx = fmaxf(mx, __shfl_xor(mx, 16));
            mx = fmaxf(mx, __shfl_xor(mx, 32));
            const float mn = fmaxf(mi[qt], mx);
            const float alpha = __expf(mi[qt] - mn);
            mi[qt] = mn;
            float rs = 0.f;
#pragma unroll
            for (int ts = 0; ts < 4; ts++) {
                const float p0 = __expf(stv[qt][ts][0] - mn);
                const float p1 = __expf(stv[qt][ts][1] - mn);
                const float p2 = __expf(stv[qt][ts][2] - mn);
                const float p3 = __expf(stv[qt][ts][3] - mn);
                rs += p0 + p1 + p2 + p3;
                bf16x4 pv = {(bf16_t)p0, (bf16_t)p1, (bf16_t)p2, (bf16_t)p3};
                *(bf16x4*)(Ps + (w * 32 + qt * 16 + m16) * 72 + ts * 16 + quad * 4) = pv;
            }
            rs += __shfl_xor(rs, 16);
            rs += __shfl_xor(rs, 32);
            li[qt] = li[qt] * alpha + rs;
#pragma unroll
            for (int ht = 0; ht < 8; ht++) ot[qt][ht] *= alpha;
        }
        __syncthreads();

        // O^T[h][q] += sum_s V^T[h][s] P^T[s][q]
#pragma unroll
        for (int ck = 0; ck < 2; ck++) {
            bf16x8 pf[2];
#pragma unroll
            for (int qt = 0; qt < 2; qt++)
                pf[qt] = *(const bf16x8*)(Ps + (w * 32 + qt * 16 + m16) * 72 + ck * 32 + quad * 8);
#pragma unroll
            for (int ht = 0; ht < 8; ht++) {
                bf16x8 vf = *(const bf16x8*)(Vs + (16 * ht + m16) * 72 + ck * 32 + quad * 8);
                ot[0][ht] = MFMA_BF16(vf, pf[0], ot[0][ht]);
                ot[1][ht] = MFMA_BF16(vf, pf[1], ot[1][ht]);
            }
        }
    }

    // write m/l partials (one lane per q-row: quad 0)
#pragma unroll
    for (int qt = 0; qt < 2; qt++) {
        if (quad == 0) {
            const int row = w * 32 + qt * 16 + m16;
            ml[pidx * 256 + row] = mi[qt];
            ml[pidx * 256 + 128 + row] = li[qt];
        }
    }

    // Epilogue: normalize by chunk-local l, transpose O^T -> O via LDS, store
    __syncthreads();
    const float inv0 = 1.f / li[0], inv1 = 1.f / li[1];
    bf16_t* Oq = smem + w * (32 * 136);
#pragma unroll
    for (int qt = 0; qt < 2; qt++) {
        const float inv = qt ? inv1 : inv0;
#pragma unroll
        for (int ht = 0; ht < 8; ht++) {
            bf16x4 v = {(bf16_t)(ot[qt][ht][0] * inv), (bf16_t)(ot[qt][ht][1] * inv),
                        (bf16_t)(ot[qt][ht][2] * inv), (bf16_t)(ot[qt][ht][3] * inv)};
            *(bf16x4*)(Oq + (qt * 16 + m16) * 136 + ht * 16 + quad * 4) = v;
        }
    }
    __syncthreads();
    {
        const int qrow = l >> 1, hf = l & 1;
        const int qloc = w * 32 + qrow;
        bf16_t* dst = Opart + (pidx * 128 + qloc) * 128 + hf * 64;
        const bf16_t* srcl = Oq + qrow * 136 + hf * 64;
#pragma unroll
        for (int j = 0; j < 8; j++) *(bf16x8*)(dst + j * 8) = *(const bf16x8*)(srcl + j * 8);
    }
}

// ---------------------------------------------------------------------------
// Combine partial attention chunks: ctx[t][n*H+h] = sum_c w_c * O_c
// ---------------------------------------------------------------------------
__global__ __launch_bounds__(256) void combine_kernel(const bf16_t* __restrict__ Opart,
                                                      const float* __restrict__ ml,
                                                      bf16_t* __restrict__ ctx) {
    const int qb = blockIdx.x, n = blockIdx.y;
    const int C = (qb + 4) >> 2;
    int f0 = 0;
    for (int i = 0; i < qb; i++) f0 += (i + 4) >> 2;
    const int tid = threadIdx.x;
    const int qrow = tid >> 1, half = tid & 1;
    const long pb = (long)n * FPH_ + f0;

    float m[4], lv[4], wv[4];
    float M = -1e30f;
    for (int c = 0; c < C; c++) {
        m[c] = ml[(pb + c) * 256 + qrow];
        lv[c] = ml[(pb + c) * 256 + 128 + qrow];
        M = fmaxf(M, m[c]);
    }
    float wsum = 0.f;
    for (int c = 0; c < C; c++) { wv[c] = lv[c] * __expf(m[c] - M); wsum += wv[c]; }
    const float invw = 1.f / wsum;
    for (int c = 0; c < C; c++) wv[c] *= invw;

    bf16_t* dst = ctx + ((long)(qb * 128 + qrow)) * (NH_ * H_) + n * H_ + half * 64;
#pragma unroll
    for (int j = 0; j < 8; j++) {
        float acc[8] = {0, 0, 0, 0, 0, 0, 0, 0};
        for (int c = 0; c < C; c++) {
            bf16x8 v = *(const bf16x8*)(Opart + ((pb + c) * 128 + qrow) * 128 + half * 64 + j * 8);
#pragma unroll
            for (int e = 0; e < 8; e++) acc[e] += wv[c] * (float)v[e];
        }
        bf16x8 o;
#pragma unroll
        for (int e = 0; e < 8; e++) o[e] = (bf16_t)acc[e];
        *(bf16x8*)(dst + j * 8) = o;
    }
}

// ---------------------------------------------------------------------------
extern "C" void kernel_launch(void* const* d_in, const int* in_sizes, int n_in,
                              void* d_out, int out_size, void* d_ws, size_t ws_size,
                              hipStream_t stream) {
    const float* x  = (const float*)d_in[0];
    const int*   ps = (const int*)d_in[1];
    const float* wq = (const float*)d_in[2];
    const float* bq = (const float*)d_in[3];
    const float* wk = (const float*)d_in[4];
    const float* bk = (const float*)d_in[5];
    const float* wv = (const float*)d_in[6];
    const float* bv = (const float*)d_in[7];
    const float* wo = (const float*)d_in[8];
    float* out = (float*)d_out;

    bf16_t* xb  = (bf16_t*)d_ws;                 // [2048][3584]    x in bf16
    bf16_t* wt  = xb + (long)T_ * D_;            // [36][128][3584] transposed qkv weights
    bf16_t* woT = wt + (long)NW_ * H_ * D_;      // [3584][3584]    woT[d][n*H+h]
    bf16_t* qkv = woT + (long)D_ * D_;           // [36][2048][128] projections
    bf16_t* vT  = qkv + (long)NW_ * T_ * H_;     // [4][128][2048]  V transposed
    bf16_t* ctx = vT + (long)KV_ * H_ * T_;      // [2048][3584]    attention output (bf16)
    // partials alias xb+wt (dead after gemm_qkv): 36.7 MB + 1.15 MB < 47.7 MB
    bf16_t* Opart = (bf16_t*)d_ws;               // [28*40][128][128] bf16
    float*  ml    = (float*)((char*)d_ws + (long)NH_ * FPH_ * 128 * 128 * 2);  // [28*40][2][128]

    const long whd = (long)D_ * H_;
    convert_f32_bf16<<<((long)T_ * D_ / 8 + 255) / 256, 256, 0, stream>>>(x, xb);
    transpose64_f32_bf16<<<dim3(H_ / 64, D_ / 64, NH_), 256, 0, stream>>>(wq, wt, D_, H_, whd, whd);
    transpose64_f32_bf16<<<dim3(H_ / 64, D_ / 64, KV_), 256, 0, stream>>>(wk, wt + (long)NH_ * whd, D_, H_, whd, whd);
    transpose64_f32_bf16<<<dim3(H_ / 64, D_ / 64, KV_), 256, 0, stream>>>(wv, wt + (long)(NH_ + KV_) * whd, D_, H_, whd, whd);
    transpose64_f32_bf16<<<dim3(D_ / 64, D_ / 64, 1), 256, 0, stream>>>(wo, woT, D_, D_, 0, 0);

    gemm_qkv_kernel<<<dim3(T_ / 128, NW_), 256, 0, stream>>>(xb, wt, bq, bk, bv, qkv);
    rope_kernel<<<(32 * T_ * 64) / 256, 256, 0, stream>>>(qkv, ps);
    transpose32_bf16<<<dim3(H_ / 32, T_ / 32, KV_), 256, 0, stream>>>(qkv + (long)(NH_ + KV_) * T_ * H_, vT,
                                                                      T_, H_, (long)T_ * H_, (long)T_ * H_);
    attn_kernel<<<dim3(FPH_, NH_), 256, 0, stream>>>(qkv, vT, Opart, ml);
    combine_kernel<<<dim3(T_ / 128, NH_), 256, 0, stream>>>(Opart, ml, ctx);
    gemm_out_kernel<<<dim3(T_ / 128, D_ / 128), 256, 0, stream>>>(ctx, woT, out);
}

// Round 5
// 523.351 us; speedup vs baseline: 1.0806x; 1.0806x over previous
//
#include <hip/hip_runtime.h>

#define AS1 __attribute__((address_space(1)))
#define AS3 __attribute__((address_space(3)))

typedef __bf16 bf16_t;
typedef __bf16 bf16x8 __attribute__((ext_vector_type(8)));
typedef __bf16 bf16x4 __attribute__((ext_vector_type(4)));
typedef float  floatx4 __attribute__((ext_vector_type(4)));

#define MFMA_BF16(a, b, c) __builtin_amdgcn_mfma_f32_16x16x32_bf16(a, b, c, 0, 0, 0)

static constexpr int T_  = 2048;
static constexpr int D_  = 3584;
static constexpr int NH_ = 28;   // query heads
static constexpr int KV_ = 4;    // kv heads
static constexpr int H_  = 128;  // head dim
static constexpr int NW_ = 36;   // 28 q + 4 k + 4 v projection heads
static constexpr int FPH_ = 40;  // split-s work items per head: sum_qb ceil((qb+1)/4)

// ---------------------------------------------------------------------------
// Elementwise fp32 -> bf16 convert (8 elems/thread)
// ---------------------------------------------------------------------------
__global__ void convert_f32_bf16(const float* __restrict__ src, bf16_t* __restrict__ dst) {
    const long i = (long)(blockIdx.x * blockDim.x + threadIdx.x) * 8;
    float4 a = ((const float4*)(src + i))[0];
    float4 b = ((const float4*)(src + i))[1];
    bf16x8 o = {(bf16_t)a.x, (bf16_t)a.y, (bf16_t)a.z, (bf16_t)a.w,
                (bf16_t)b.x, (bf16_t)b.y, (bf16_t)b.z, (bf16_t)b.w};
    *(bf16x8*)(dst + i) = o;
}

// ---------------------------------------------------------------------------
// 64x64-tile fp32 -> bf16 transpose, vectorized: dst[c][r] = (bf16)src[r][c]
// ---------------------------------------------------------------------------
__global__ __launch_bounds__(256) void transpose64_f32_bf16(const float* __restrict__ src,
                                                            bf16_t* __restrict__ dst,
                                                            int R, int C, long sStride, long dStride) {
    __shared__ bf16_t t[64][68];
    src += (long)blockIdx.z * sStride;
    dst += (long)blockIdx.z * dStride;
    const int tid = threadIdx.x;
    const int r0 = blockIdx.y * 64, c0 = blockIdx.x * 64;
#pragma unroll
    for (int p = 0; p < 4; p++) {
        const int row = (tid >> 4) + p * 16, col4 = tid & 15;
        float4 v = *(const float4*)(src + (long)(r0 + row) * C + c0 + col4 * 4);
        bf16x4 b = {(bf16_t)v.x, (bf16_t)v.y, (bf16_t)v.z, (bf16_t)v.w};
        *(bf16x4*)&t[row][col4 * 4] = b;
    }
    __syncthreads();
#pragma unroll
    for (int p = 0; p < 2; p++) {
        const int cc = (tid >> 3) + p * 32, k = tid & 7;
        bf16x8 o;
#pragma unroll
        for (int j = 0; j < 8; j++) o[j] = t[8 * k + j][cc];
        *(bf16x8*)(dst + (long)(c0 + cc) * R + r0 + 8 * k) = o;
    }
}

// ---------------------------------------------------------------------------
// Small 32x32 bf16 transpose (used for V^T only, 2 MB)
// ---------------------------------------------------------------------------
__global__ void transpose32_bf16(const bf16_t* __restrict__ src, bf16_t* __restrict__ dst,
                                 int R, int C, long sStride, long dStride) {
    __shared__ bf16_t tile[32][33];
    src += (long)blockIdx.z * sStride;
    dst += (long)blockIdx.z * dStride;
    const int tx = threadIdx.x & 31, ty = threadIdx.x >> 5;
    const int r0 = blockIdx.y * 32, c0 = blockIdx.x * 32;
#pragma unroll
    for (int i = 0; i < 4; i++) {
        int rr = ty + i * 8;
        tile[rr][tx] = src[(long)(r0 + rr) * C + c0 + tx];
    }
    __syncthreads();
#pragma unroll
    for (int i = 0; i < 4; i++) {
        int cc = ty + i * 8;
        dst[(long)(c0 + cc) * R + r0 + tx] = tile[tx][cc];
    }
}

// ---------------------------------------------------------------------------
// m97-style 128x128 GEMM core: C = A[128 x K] * Bt[128 x K]^T, fp32 acc.
// ---------------------------------------------------------------------------
__device__ __forceinline__ void gemm_core_128x128(const bf16_t* __restrict__ Arows, int lda,
                                                  const bf16_t* __restrict__ Brows, int ldb,
                                                  int K, floatx4 acc[4][4]) {
    __shared__ bf16_t As[128 * 32];
    __shared__ bf16_t Bs[128 * 32];
    const int tid = threadIdx.x;
    const int w = tid >> 6, l = tid & 63;
    const int lr = l >> 2, lc = l & 3;
    const int m16 = l & 15, quad = l >> 4;
    const int wr = w >> 1, wc = w & 1;
#pragma unroll
    for (int i = 0; i < 4; i++)
#pragma unroll
        for (int j = 0; j < 4; j++) acc[i][j] = (floatx4){0.f, 0.f, 0.f, 0.f};

    for (int kt = 0; kt < K; kt += 32) {
        __syncthreads();
#pragma unroll
        for (int is = 0; is < 2; is++) {
            const int row = 32 * w + 16 * is + lr;
            __builtin_amdgcn_global_load_lds((const AS1 void*)(Arows + (long)row * lda + kt + lc * 8),
                                             (AS3 void*)(As + row * 32 + lc * 8), 16, 0, 0);
            __builtin_amdgcn_global_load_lds((const AS1 void*)(Brows + (long)row * ldb + kt + lc * 8),
                                             (AS3 void*)(Bs + row * 32 + lc * 8), 16, 0, 0);
        }
        __syncthreads();
        bf16x8 af[4], bfr[4];
#pragma unroll
        for (int i = 0; i < 4; i++)
            af[i] = *(const bf16x8*)(As + (64 * wr + 16 * i + m16) * 32 + quad * 8);
#pragma unroll
        for (int j = 0; j < 4; j++)
            bfr[j] = *(const bf16x8*)(Bs + (64 * wc + 16 * j + m16) * 32 + quad * 8);
#pragma unroll
        for (int i = 0; i < 4; i++)
#pragma unroll
            for (int j = 0; j < 4; j++) acc[i][j] = MFMA_BF16(af[i], bfr[j], acc[i][j]);
    }
}

// QKV projection: out[hd][t][h] = x[t][:] . w[hd][:][h] + bias[hd][h]
__global__ __launch_bounds__(256) void gemm_qkv_kernel(const bf16_t* __restrict__ X,
                                                       const bf16_t* __restrict__ Wt,
                                                       const float* __restrict__ bq,
                                                       const float* __restrict__ bk,
                                                       const float* __restrict__ bv,
                                                       bf16_t* __restrict__ out) {
    const int mt = blockIdx.x, hd = blockIdx.y;
    const float* bias = hd < NH_ ? bq + hd * H_
                                 : (hd < NH_ + KV_ ? bk + (hd - NH_) * H_ : bv + (hd - NH_ - KV_) * H_);
    floatx4 acc[4][4];
    gemm_core_128x128(X + (long)mt * 128 * D_, D_, Wt + (long)hd * H_ * D_, D_, D_, acc);
    const int l = threadIdx.x & 63, w = threadIdx.x >> 6;
    const int m16 = l & 15, quad = l >> 4, wr = w >> 1, wc = w & 1;
    bf16_t* C = out + (long)hd * T_ * H_ + (long)mt * 128 * H_;
#pragma unroll
    for (int j = 0; j < 4; j++) {
        const int col = 64 * wc + 16 * j + m16;
        const float bb = bias[col];
#pragma unroll
        for (int i = 0; i < 4; i++) {
            const int row = 64 * wr + 16 * i + quad * 4;
#pragma unroll
            for (int r = 0; r < 4; r++) C[(row + r) * H_ + col] = (bf16_t)(acc[i][j][r] + bb);
        }
    }
}

// Output projection: out[t][d] = ctx[t][:] . woT[d][:]  (fp32 output)
__global__ __launch_bounds__(256) void gemm_out_kernel(const bf16_t* __restrict__ A,
                                                       const bf16_t* __restrict__ Bt,
                                                       float* __restrict__ Cg) {
    const int mt = blockIdx.x, nt = blockIdx.y;
    floatx4 acc[4][4];
    gemm_core_128x128(A + (long)mt * 128 * D_, D_, Bt + (long)nt * 128 * D_, D_, D_, acc);
    const int l = threadIdx.x & 63, w = threadIdx.x >> 6;
    const int m16 = l & 15, quad = l >> 4, wr = w >> 1, wc = w & 1;
    float* C = Cg + (long)mt * 128 * D_ + nt * 128;
#pragma unroll
    for (int j = 0; j < 4; j++) {
        const int col = 64 * wc + 16 * j + m16;
#pragma unroll
        for (int i = 0; i < 4; i++) {
            const int row = 64 * wr + 16 * i + quad * 4;
#pragma unroll
            for (int r = 0; r < 4; r++) C[(long)(row + r) * D_ + col] = acc[i][j][r];
        }
    }
}

// ---------------------------------------------------------------------------
// In-place RoPE on q (heads 0..27, scaled by H^-0.5) and k (heads 28..31)
// ---------------------------------------------------------------------------
__global__ void rope_kernel(bf16_t* __restrict__ qkv, const int* __restrict__ pos) {
    const int idx = blockIdx.x * blockDim.x + threadIdx.x;
    const int h = idx & 63;
    const int t = (idx >> 6) & (T_ - 1);
    const int hd = idx >> 17;
    if (hd >= NH_ + KV_) return;
    bf16_t* p = qkv + ((long)hd * T_ + t) * H_;
    const float x1 = (float)p[h], x2 = (float)p[h + 64];
    const float inv = expf(-(float)h * (13.815510557964274f / 64.f));
    const float ang = (float)pos[t] * inv;
    float s, c;
    sincosf(ang, &s, &c);
    float o1 = x1 * c - x2 * s;
    float o2 = x2 * c + x1 * s;
    if (hd < NH_) { o1 *= 0.08838834764831845f; o2 *= 0.08838834764831845f; }
    p[h] = (bf16_t)o1;
    p[h + 64] = (bf16_t)o2;
}

// ---------------------------------------------------------------------------
// Split-s flash attention. Work item = (head, q-tile of 128, s-chunk of 512).
// NOTE: __launch_bounds__(256) only — forcing 3 waves/EU clamped VGPRs to 84
// and caused ~290 MB of scratch spill traffic per dispatch (R4 counters).
// ---------------------------------------------------------------------------
__global__ __launch_bounds__(256) void attn_kernel(const bf16_t* __restrict__ qkv,
                                                   const bf16_t* __restrict__ vT,
                                                   bf16_t* __restrict__ Opart,
                                                   float* __restrict__ ml) {
    __shared__ bf16_t smem[64 * 136 + 128 * 72 + 128 * 72];
    bf16_t* Ks = smem;
    bf16_t* Vs = smem + 64 * 136;
    bf16_t* Ps = Vs + 128 * 72;

    const int n = blockIdx.y;
    int qb = 0, rem = blockIdx.x;
    while (true) { int ch = (qb + 4) >> 2; if (rem < ch) break; rem -= ch; qb++; }
    const long pidx = (long)n * FPH_ + blockIdx.x;

    const int kvh = n / 7;
    const bf16_t* Q = qkv + (long)n * T_ * H_;
    const bf16_t* Kg = qkv + (long)(NH_ + kvh) * T_ * H_;
    const bf16_t* Vg = vT + (long)kvh * H_ * T_;  // [h][t]

    const int tid = threadIdx.x, w = tid >> 6, l = tid & 63;
    const int m16 = l & 15, quad = l >> 4;
    const int q0 = qb * 128 + w * 32;

    bf16x8 qf[2][4];
#pragma unroll
    for (int qt = 0; qt < 2; qt++)
#pragma unroll
        for (int kk = 0; kk < 4; kk++)
            qf[qt][kk] = *(const bf16x8*)(Q + (long)(q0 + qt * 16 + m16) * H_ + kk * 32 + quad * 8);

    floatx4 ot[2][8];
#pragma unroll
    for (int qt = 0; qt < 2; qt++)
#pragma unroll
        for (int ht = 0; ht < 8; ht++) ot[qt][ht] = (floatx4){0.f, 0.f, 0.f, 0.f};
    float mi[2] = {-1e30f, -1e30f}, li[2] = {0.f, 0.f};

    const int sb0 = rem * 8;
    const int sbE = min(sb0 + 8, 2 * qb + 2);
    const int ks_row = tid >> 2, ks_ck = (tid & 3) * 32;
    const int vs_row = tid >> 1, vs_hf = (tid & 1) * 32;

    // prefetch first tile into registers
    bf16x8 ka[4], va[4];
    {
        const bf16x8* g = (const bf16x8*)(Kg + ((long)sb0 * 64 + ks_row) * H_ + ks_ck);
#pragma unroll
        for (int i = 0; i < 4; i++) ka[i] = g[i];
        const bf16x8* gv = (const bf16x8*)(Vg + (long)vs_row * T_ + sb0 * 64 + vs_hf);
#pragma unroll
        for (int i = 0; i < 4; i++) va[i] = gv[i];
    }

    for (int sb = sb0; sb < sbE; sb++) {
        __syncthreads();
        {
            bf16x8* d = (bf16x8*)(Ks + ks_row * 136 + ks_ck);
#pragma unroll
            for (int i = 0; i < 4; i++) d[i] = ka[i];
            bf16x8* dv = (bf16x8*)(Vs + vs_row * 72 + vs_hf);
#pragma unroll
            for (int i = 0; i < 4; i++) dv[i] = va[i];
        }
        __syncthreads();
        if (sb + 1 < sbE) {  // prefetch next tile while computing
            const bf16x8* g = (const bf16x8*)(Kg + ((long)(sb + 1) * 64 + ks_row) * H_ + ks_ck);
#pragma unroll
            for (int i = 0; i < 4; i++) ka[i] = g[i];
            const bf16x8* gv = (const bf16x8*)(Vg + (long)vs_row * T_ + (sb + 1) * 64 + vs_hf);
#pragma unroll
            for (int i = 0; i < 4; i++) va[i] = gv[i];
        }

        // S^T[s][q] = sum_h K[s][h] Q[q][h]
        floatx4 stv[2][4];
#pragma unroll
        for (int ts = 0; ts < 4; ts++) {
            bf16x8 kf[4];
#pragma unroll
            for (int kk = 0; kk < 4; kk++)
                kf[kk] = *(const bf16x8*)(Ks + (16 * ts + m16) * 136 + kk * 32 + quad * 8);
#pragma unroll
            for (int qt = 0; qt < 2; qt++) {
                floatx4 c = (floatx4){0.f, 0.f, 0.f, 0.f};
#pragma unroll
                for (int kk = 0; kk < 4; kk++) c = MFMA_BF16(kf[kk], qf[qt][kk], c);
                stv[qt][ts] = c;
            }
        }

        const bool need_mask = (sb * 64 + 63) > q0;
#pragma unroll
        for (int qt = 0; qt < 2; qt++) {
            const int qg = q0 + qt * 16 + m16;
            if (need_mask) {
#pragma unroll
                for (int ts = 0; ts < 4; ts++)
#pragma unroll
                    for (int r = 0; r < 4; r++) {
                        const int sg = sb * 64 + ts * 16 + quad * 4 + r;
                        if (sg > qg) stv[qt][ts][r] = -1e30f;
                    }
            }
            float mx = -1e30f;
#pragma unroll
            for (int ts = 0; ts < 4; ts++)
#pragma unroll
                for (int r = 0; r < 4; r++) mx = fmaxf(mx, stv[qt][ts][r]);
            mx = fmaxf(mx, __shfl_xor(mx, 16));
            mx = fmaxf(mx, __shfl_xor(mx, 32));
            const float mn = fmaxf(mi[qt], mx);
            const float alpha = __expf(mi[qt] - mn);
            mi[qt] = mn;
            float rs = 0.f;
#pragma unroll
            for (int ts = 0; ts < 4; ts++) {
                const float p0 = __expf(stv[qt][ts][0] - mn);
                const float p1 = __expf(stv[qt][ts][1] - mn);
                const float p2 = __expf(stv[qt][ts][2] - mn);
                const float p3 = __expf(stv[qt][ts][3] - mn);
                rs += p0 + p1 + p2 + p3;
                bf16x4 pv = {(bf16_t)p0, (bf16_t)p1, (bf16_t)p2, (bf16_t)p3};
                *(bf16x4*)(Ps + (w * 32 + qt * 16 + m16) * 72 + ts * 16 + quad * 4) = pv;
            }
            rs += __shfl_xor(rs, 16);
            rs += __shfl_xor(rs, 32);
            li[qt] = li[qt] * alpha + rs;
#pragma unroll
            for (int ht = 0; ht < 8; ht++) ot[qt][ht] *= alpha;
        }
        __syncthreads();

        // O^T[h][q] += sum_s V^T[h][s] P^T[s][q]
#pragma unroll
        for (int ck = 0; ck < 2; ck++) {
            bf16x8 pf[2];
#pragma unroll
            for (int qt = 0; qt < 2; qt++)
                pf[qt] = *(const bf16x8*)(Ps + (w * 32 + qt * 16 + m16) * 72 + ck * 32 + quad * 8);
#pragma unroll
            for (int ht = 0; ht < 8; ht++) {
                bf16x8 vf = *(const bf16x8*)(Vs + (16 * ht + m16) * 72 + ck * 32 + quad * 8);
                ot[0][ht] = MFMA_BF16(vf, pf[0], ot[0][ht]);
                ot[1][ht] = MFMA_BF16(vf, pf[1], ot[1][ht]);
            }
        }
    }

    // write m/l partials (one lane per q-row: quad 0)
#pragma unroll
    for (int qt = 0; qt < 2; qt++) {
        if (quad == 0) {
            const int row = w * 32 + qt * 16 + m16;
            ml[pidx * 256 + row] = mi[qt];
            ml[pidx * 256 + 128 + row] = li[qt];
        }
    }

    // Epilogue: normalize by chunk-local l, transpose O^T -> O via LDS, store
    __syncthreads();
    const float inv0 = 1.f / li[0], inv1 = 1.f / li[1];
    bf16_t* Oq = smem + w * (32 * 136);
#pragma unroll
    for (int qt = 0; qt < 2; qt++) {
        const float inv = qt ? inv1 : inv0;
#pragma unroll
        for (int ht = 0; ht < 8; ht++) {
            bf16x4 v = {(bf16_t)(ot[qt][ht][0] * inv), (bf16_t)(ot[qt][ht][1] * inv),
                        (bf16_t)(ot[qt][ht][2] * inv), (bf16_t)(ot[qt][ht][3] * inv)};
            *(bf16x4*)(Oq + (qt * 16 + m16) * 136 + ht * 16 + quad * 4) = v;
        }
    }
    __syncthreads();
    {
        const int qrow = l >> 1, hf = l & 1;
        const int qloc = w * 32 + qrow;
        bf16_t* dst = Opart + (pidx * 128 + qloc) * 128 + hf * 64;
        const bf16_t* srcl = Oq + qrow * 136 + hf * 64;
#pragma unroll
        for (int j = 0; j < 8; j++) *(bf16x8*)(dst + j * 8) = *(const bf16x8*)(srcl + j * 8);
    }
}

// ---------------------------------------------------------------------------
// Combine partial attention chunks: ctx[t][n*H+h] = sum_c w_c * O_c
// ---------------------------------------------------------------------------
__global__ __launch_bounds__(256) void combine_kernel(const bf16_t* __restrict__ Opart,
                                                      const float* __restrict__ ml,
                                                      bf16_t* __restrict__ ctx) {
    const int qb = blockIdx.x, n = blockIdx.y;
    const int C = (qb + 4) >> 2;
    int f0 = 0;
    for (int i = 0; i < qb; i++) f0 += (i + 4) >> 2;
    const int tid = threadIdx.x;
    const int qrow = tid >> 1, half = tid & 1;
    const long pb = (long)n * FPH_ + f0;

    float m[4], lv[4], wv[4];
    float M = -1e30f;
    for (int c = 0; c < C; c++) {
        m[c] = ml[(pb + c) * 256 + qrow];
        lv[c] = ml[(pb + c) * 256 + 128 + qrow];
        M = fmaxf(M, m[c]);
    }
    float wsum = 0.f;
    for (int c = 0; c < C; c++) { wv[c] = lv[c] * __expf(m[c] - M); wsum += wv[c]; }
    const float invw = 1.f / wsum;
    for (int c = 0; c < C; c++) wv[c] *= invw;

    bf16_t* dst = ctx + ((long)(qb * 128 + qrow)) * (NH_ * H_) + n * H_ + half * 64;
#pragma unroll
    for (int j = 0; j < 8; j++) {
        float acc[8] = {0, 0, 0, 0, 0, 0, 0, 0};
        for (int c = 0; c < C; c++) {
            bf16x8 v = *(const bf16x8*)(Opart + ((pb + c) * 128 + qrow) * 128 + half * 64 + j * 8);
#pragma unroll
            for (int e = 0; e < 8; e++) acc[e] += wv[c] * (float)v[e];
        }
        bf16x8 o;
#pragma unroll
        for (int e = 0; e < 8; e++) o[e] = (bf16_t)acc[e];
        *(bf16x8*)(dst + j * 8) = o;
    }
}

// ---------------------------------------------------------------------------
extern "C" void kernel_launch(void* const* d_in, const int* in_sizes, int n_in,
                              void* d_out, int out_size, void* d_ws, size_t ws_size,
                              hipStream_t stream) {
    const float* x  = (const float*)d_in[0];
    const int*   ps = (const int*)d_in[1];
    const float* wq = (const float*)d_in[2];
    const float* bq = (const float*)d_in[3];
    const float* wk = (const float*)d_in[4];
    const float* bk = (const float*)d_in[5];
    const float* wv = (const float*)d_in[6];
    const float* bv = (const float*)d_in[7];
    const float* wo = (const float*)d_in[8];
    float* out = (float*)d_out;

    bf16_t* xb  = (bf16_t*)d_ws;                 // [2048][3584]    x in bf16
    bf16_t* wt  = xb + (long)T_ * D_;            // [36][128][3584] transposed qkv weights
    bf16_t* woT = wt + (long)NW_ * H_ * D_;      // [3584][3584]    woT[d][n*H+h]
    bf16_t* qkv = woT + (long)D_ * D_;           // [36][2048][128] projections
    bf16_t* vT  = qkv + (long)NW_ * T_ * H_;     // [4][128][2048]  V transposed
    bf16_t* ctx = vT + (long)KV_ * H_ * T_;      // [2048][3584]    attention output (bf16)
    // partials alias xb+wt (dead after gemm_qkv): 36.7 MB + 1.15 MB < 47.7 MB
    bf16_t* Opart = (bf16_t*)d_ws;               // [28*40][128][128] bf16
    float*  ml    = (float*)((char*)d_ws + (long)NH_ * FPH_ * 128 * 128 * 2);  // [28*40][2][128]

    const long whd = (long)D_ * H_;
    convert_f32_bf16<<<((long)T_ * D_ / 8 + 255) / 256, 256, 0, stream>>>(x, xb);
    transpose64_f32_bf16<<<dim3(H_ / 64, D_ / 64, NH_), 256, 0, stream>>>(wq, wt, D_, H_, whd, whd);
    transpose64_f32_bf16<<<dim3(H_ / 64, D_ / 64, KV_), 256, 0, stream>>>(wk, wt + (long)NH_ * whd, D_, H_, whd, whd);
    transpose64_f32_bf16<<<dim3(H_ / 64, D_ / 64, KV_), 256, 0, stream>>>(wv, wt + (long)(NH_ + KV_) * whd, D_, H_, whd, whd);
    transpose64_f32_bf16<<<dim3(D_ / 64, D_ / 64, 1), 256, 0, stream>>>(wo, woT, D_, D_, 0, 0);

    gemm_qkv_kernel<<<dim3(T_ / 128, NW_), 256, 0, stream>>>(xb, wt, bq, bk, bv, qkv);
    rope_kernel<<<(32 * T_ * 64) / 256, 256, 0, stream>>>(qkv, ps);
    transpose32_bf16<<<dim3(H_ / 32, T_ / 32, KV_), 256, 0, stream>>>(qkv + (long)(NH_ + KV_) * T_ * H_, vT,
                                                                      T_, H_, (long)T_ * H_, (long)T_ * H_);
    attn_kernel<<<dim3(FPH_, NH_), 256, 0, stream>>>(qkv, vT, Opart, ml);
    combine_kernel<<<dim3(T_ / 128, NH_), 256, 0, stream>>>(Opart, ml, ctx);
    gemm_out_kernel<<<dim3(T_ / 128, D_ / 128), 256, 0, stream>>>(ctx, woT, out);
}